// Round 1
// baseline (454.884 us; speedup 1.0000x reference)
//
#include <hip/hip_runtime.h>
#include <hip/hip_bf16.h>
#include <math.h>

#define BQ 32
#define SQ 2048
#define DQ 1024
#define NQ 512
#define MQ (BQ*SQ)
#define SS 16

typedef __attribute__((ext_vector_type(8))) short bf16x8;
typedef __attribute__((ext_vector_type(4))) float f32x4;

__device__ __forceinline__ short f2bf(float f){
  unsigned u = __float_as_uint(f);
  u = u + 0x7FFFu + ((u >> 16) & 1u);
  return (short)(u >> 16);
}

// ---- prep: transpose gate_w1 [K=1024][N=512] -> bf16 w1t [N=512][K=1024]
__global__ void k_w1t(const float* __restrict__ w1, short* __restrict__ w1t){
  int i = blockIdx.x*256 + threadIdx.x;
  if (i >= NQ*DQ) return;
  int n = i >> 10, k = i & (DQ-1);
  w1t[i] = f2bf(w1[(size_t)k*NQ + n]);
}

// ---- prep: wq[d] = key_w[d,:]·q (d<1024); wq[1024] = key_b·q
__global__ void k_wq(const float* __restrict__ kw, const float* __restrict__ kb,
                     const float* __restrict__ q, float* __restrict__ wq){
  __shared__ float sh[4];
  int d = blockIdx.x, t = threadIdx.x;
  const float* row = (d < DQ) ? (kw + (size_t)d*DQ) : kb;
  float s = 0.f;
  for (int e=t;e<DQ;e+=256) s += row[e]*q[e];
  #pragma unroll
  for (int o=32;o;o>>=1) s += __shfl_down(s,o);
  if ((t&63)==0) sh[t>>6]=s;
  __syncthreads();
  if (t==0) wq[d] = sh[0]+sh[1]+sh[2]+sh[3];
}

// ---- mask dtype detector: 0=int32(0/1), 1=float32(0/1.0f), 2=byte(bool)
__global__ void k_det(const unsigned int* __restrict__ m, int* __restrict__ flag){
  __shared__ int so, sf;
  int t = threadIdx.x;
  if (t==0){ so=0; sf=0; }
  __syncthreads();
  int o=0, f1=0;
  for (int i=t;i<MQ/4;i+=256){
    unsigned v = m[i];
    if (v==0x3F800000u) f1=1;
    else if (v>1u) o=1;
  }
  if (o) atomicOr(&so,1);
  if (f1) atomicOr(&sf,1);
  __syncthreads();
  if (t==0) *flag = so?2:(sf?1:0);
}

// ---- fused: h=GELU(x@W1+b1); glogit=h@w2; gate=sigmoid(glogit+b2); xq=x·wq
// tile: 64 rows x 512 cols, 8 waves (2 m-waves x 4 n-waves), MFMA 16x16x32 bf16
__global__ __launch_bounds__(512) void k_gate(
    const float* __restrict__ x, const short* __restrict__ w1t,
    const float* __restrict__ wq, const float* __restrict__ w2,
    const float* __restrict__ b1, const float* __restrict__ b2p,
    float* __restrict__ gate, float* __restrict__ xq)
{
  __shared__ float red[4][64];
  int m0 = blockIdx.x*64;
  int tid = threadIdx.x;
  int lane = tid & 63;
  int wid = tid >> 6;
  int wm = wid >> 2, wn = wid & 3;
  int lo = lane & 15, hi = lane >> 4;

  float w2v[8], b1v[8];
  #pragma unroll
  for (int fn=0; fn<8; fn++){
    int n = wn*128 + fn*16 + lo;
    w2v[fn] = w2[n];
    b1v[fn] = b1[n];
  }

  f32x4 acc[2][8];
  #pragma unroll
  for (int a=0;a<2;a++)
    #pragma unroll
    for (int bb=0;bb<8;bb++) acc[a][bb] = (f32x4){0.f,0.f,0.f,0.f};

  float xqa0=0.f, xqa1=0.f;

  const float* abase0 = x + (size_t)(m0 + wm*32 + lo)*DQ + hi*8;   // fm=0 rows
  const float* abase1 = abase0 + (size_t)16*DQ;                     // fm=1 rows
  const short* wbase  = w1t + (size_t)(wn*128 + lo)*DQ + hi*8;
  const float* qbase  = wq + hi*8;

  for (int k0=0; k0<DQ; k0+=32){
    f32x4 a0 = *(const f32x4*)(abase0 + k0);
    f32x4 a1 = *(const f32x4*)(abase0 + k0 + 4);
    f32x4 c0 = *(const f32x4*)(abase1 + k0);
    f32x4 c1 = *(const f32x4*)(abase1 + k0 + 4);
    bf16x8 af0, af1;
    #pragma unroll
    for (int j=0;j<4;j++){
      af0[j]   = f2bf(a0[j]);  af0[4+j] = f2bf(a1[j]);
      af1[j]   = f2bf(c0[j]);  af1[4+j] = f2bf(c1[j]);
    }
    if (wn==0){
      f32x4 q0 = *(const f32x4*)(qbase + k0);
      f32x4 q1 = *(const f32x4*)(qbase + k0 + 4);
      #pragma unroll
      for (int j=0;j<4;j++){
        xqa0 += a0[j]*q0[j] + a1[j]*q1[j];
        xqa1 += c0[j]*q0[j] + c1[j]*q1[j];
      }
    }
    #pragma unroll
    for (int fn=0;fn<8;fn++){
      bf16x8 bf = *(const bf16x8*)(wbase + (size_t)fn*16*DQ + k0);
      acc[0][fn] = __builtin_amdgcn_mfma_f32_16x16x32_bf16(af0, bf, acc[0][fn], 0,0,0);
      acc[1][fn] = __builtin_amdgcn_mfma_f32_16x16x32_bf16(af1, bf, acc[1][fn], 0,0,0);
    }
  }

  // xq: reduce partial k-sums across the 4 hi-groups
  if (wn==0){
    float v0 = xqa0; v0 += __shfl_xor(v0,16); v0 += __shfl_xor(v0,32);
    float v1 = xqa1; v1 += __shfl_xor(v1,16); v1 += __shfl_xor(v1,32);
    if (lane<16){
      xq[m0 + wm*32 + lane]      = v0;
      xq[m0 + wm*32 + 16 + lane] = v1;
    }
  }

  // gate: GELU + dot w2 (sum over this wave's 128 cols), then cross-wave reduce
  #pragma unroll
  for (int fm=0;fm<2;fm++){
    #pragma unroll
    for (int j=0;j<4;j++){
      float s = 0.f;
      #pragma unroll
      for (int fn=0;fn<8;fn++){
        float h = acc[fm][fn][j] + b1v[fn];
        float g = 0.5f*h*(1.0f + erff(h*0.70710678118f));
        s += g*w2v[fn];
      }
      #pragma unroll
      for (int o=1;o<16;o<<=1) s += __shfl_xor(s,o);
      if (lo==0) red[wn][wm*32 + fm*16 + hi*4 + j] = s;
    }
  }
  __syncthreads();
  if (wid==0){
    float g = red[0][lane]+red[1][lane]+red[2][lane]+red[3][lane] + b2p[0];
    gate[m0+lane] = 1.0f/(1.0f+expf(-g));
  }
}

// ---- per-batch masked softmax with chronological decay; writes wgt = alpha*gate
__device__ __forceinline__ float bredsum(float v, float* sh){
  #pragma unroll
  for (int o=32;o;o>>=1) v += __shfl_down(v,o);
  __syncthreads();
  if ((threadIdx.x&63)==0) sh[threadIdx.x>>6]=v;
  __syncthreads();
  return sh[0]+sh[1]+sh[2]+sh[3];
}
__device__ __forceinline__ float bredmax(float v, float* sh){
  #pragma unroll
  for (int o=32;o;o>>=1) v = fmaxf(v,__shfl_down(v,o));
  __syncthreads();
  if ((threadIdx.x&63)==0) sh[threadIdx.x>>6]=v;
  __syncthreads();
  return fmaxf(fmaxf(sh[0],sh[1]),fmaxf(sh[2],sh[3]));
}

__global__ __launch_bounds__(256) void k_soft(
    const void* __restrict__ maskp, const int* __restrict__ flag,
    const float* __restrict__ gate, const float* __restrict__ xqv,
    const float* __restrict__ wq, const float* __restrict__ lamp,
    float* __restrict__ wgt)
{
  __shared__ float sh[4];
  int b = blockIdx.x, t = threadIdx.x;
  int fl = *flag;
  const unsigned char* m8 = (const unsigned char*)maskp;
  const float* mf = (const float*)maskp;
  const int* mi = (const int*)maskp;
  size_t base = (size_t)b*SQ;
  int cnt = 0;
  int msk[8];
  #pragma unroll
  for (int i=0;i<8;i++){
    int s = t + i*256;
    size_t idx = base + s;
    int mm = (fl==2) ? (m8[idx]!=0) : (fl==1) ? (mf[idx]!=0.0f) : (mi[idx]!=0);
    msk[i]=mm; cnt += mm^1;
  }
  float L = bredsum((float)cnt, sh);
  float qb = wq[DQ];
  float lam = lamp[0];
  float posl = fmaxf(lam,0.f) + log1pf(expf(-fabsf(lam)));
  const float inv = 0.03125f; // 1/sqrt(1024)
  float dec[8];
  float mx = -3.0e38f;
  #pragma unroll
  for (int i=0;i<8;i++){
    int s = t + i*256;
    size_t r = base + s;
    float lg = (gate[r]*xqv[r] + qb)*inv;
    float pen = fmaxf(L - 1.0f - (float)s, 0.0f);
    float d = lg - posl*pen;
    if (msk[i]) d = -10000.0f;
    dec[i]=d; mx = fmaxf(mx,d);
  }
  mx = bredmax(mx, sh);
  float ssum = 0.f;
  #pragma unroll
  for (int i=0;i<8;i++){ dec[i] = expf(dec[i]-mx); ssum += dec[i]; }
  ssum = bredsum(ssum, sh);
  float rinv = 1.0f/ssum;
  #pragma unroll
  for (int i=0;i<8;i++){
    size_t r = base + t + i*256;
    wgt[r] = dec[i]*rinv*gate[r];
  }
}

// ---- weighted pooling: partials over S chunks
__global__ __launch_bounds__(256) void k_pool(
    const float* __restrict__ x, const float* __restrict__ wgt,
    float* __restrict__ part)
{
  int b = blockIdx.x, sc = blockIdx.y, t = threadIdx.x;
  const int SCH = SQ/SS; // 128
  const float* xb = x + ((size_t)b*SQ + (size_t)sc*SCH)*DQ + t*4;
  const float* wb = wgt + (size_t)b*SQ + (size_t)sc*SCH;
  f32x4 a = {0.f,0.f,0.f,0.f};
  #pragma unroll 4
  for (int s=0;s<SCH;s++){
    float w = wb[s];
    f32x4 v = *(const f32x4*)(xb + (size_t)s*DQ);
    a[0] += w*v[0]; a[1] += w*v[1]; a[2] += w*v[2]; a[3] += w*v[3];
  }
  *(f32x4*)(part + ((size_t)sc*BQ + b)*DQ + t*4) = a;
}

__global__ __launch_bounds__(256) void k_fin(const float* __restrict__ part, float* __restrict__ out){
  int i = blockIdx.x*256 + threadIdx.x;
  float s = 0.f;
  #pragma unroll
  for (int c=0;c<SS;c++) s += part[(size_t)c*(BQ*DQ) + i];
  out[i]=s;
}

extern "C" void kernel_launch(void* const* d_in, const int* in_sizes, int n_in,
                              void* d_out, int out_size, void* d_ws, size_t ws_size,
                              hipStream_t stream)
{
  const float* x    = (const float*)d_in[0];
  const void*  mask = d_in[1];
  const float* w1   = (const float*)d_in[2];
  const float* b1   = (const float*)d_in[3];
  const float* w2   = (const float*)d_in[4];
  const float* b2   = (const float*)d_in[5];
  const float* lam  = (const float*)d_in[6];
  const float* q    = (const float*)d_in[7];
  const float* kw   = (const float*)d_in[8];
  const float* kb   = (const float*)d_in[9];
  char* ws = (char*)d_ws;
  short* w1t = (short*)ws;                           // 1 MB
  float* wq  = (float*)(ws + (1<<20));               // 8 KB (1025 floats)
  int* flag  = (int*)(ws + (1<<20) + 8192);          // 256 B
  float* gate= (float*)(ws + (1<<20) + 8448);        // 256 KB
  float* xq  = gate + MQ;                            // 256 KB
  float* wgt = xq + MQ;                              // 256 KB
  float* part= wgt + MQ;                             // 2 MB
  float* out = (float*)d_out;

  k_w1t<<<dim3((NQ*DQ+255)/256), 256, 0, stream>>>(w1, w1t);
  k_wq<<<dim3(DQ+1), 256, 0, stream>>>(kw, kb, q, wq);
  k_det<<<dim3(1), 256, 0, stream>>>((const unsigned int*)mask, flag);
  k_gate<<<dim3(MQ/64), 512, 0, stream>>>(x, w1t, wq, w2, b1, b2, gate, xq);
  k_soft<<<dim3(BQ), 256, 0, stream>>>(mask, flag, gate, xq, wq, lam, wgt);
  k_pool<<<dim3(BQ, SS), 256, 0, stream>>>(x, wgt, part);
  k_fin<<<dim3((BQ*DQ)/256), 256, 0, stream>>>(part, out);
}

// Round 3
// 326.977 us; speedup vs baseline: 1.3912x; 1.3912x over previous
//
#include <hip/hip_runtime.h>
#include <hip/hip_bf16.h>
#include <math.h>

#define BQ 32
#define SQ 2048
#define DQ 1024
#define NQ 512
#define MQ (BQ*SQ)
#define SS 16
#define BM 128
#define BN 128
#define BK 32

typedef __attribute__((ext_vector_type(8))) short bf16x8;
typedef __attribute__((ext_vector_type(4))) float f32x4;

__device__ __forceinline__ short f2bf(float f){
  unsigned u = __float_as_uint(f);
  u = u + 0x7FFFu + ((u >> 16) & 1u);
  return (short)(u >> 16);
}

__device__ __forceinline__ void gload_lds16(const void* g, void* l){
  __builtin_amdgcn_global_load_lds(
      (const __attribute__((address_space(1))) unsigned int*)g,
      (__attribute__((address_space(3))) unsigned int*)l, 16, 0, 0);
}

// ---- prep: transpose gate_w1 [K=1024][N=512] -> bf16 w1t [N=512][K=1024]
__global__ void k_w1t(const float* __restrict__ w1, short* __restrict__ w1t){
  int i = blockIdx.x*256 + threadIdx.x;
  if (i >= NQ*DQ) return;
  int n = i >> 10, k = i & (DQ-1);
  w1t[i] = f2bf(w1[(size_t)k*NQ + n]);
}

// ---- prep: wq[d] = key_w[d,:]·q (d<1024); wq[1024] = key_b·q
__global__ void k_wq(const float* __restrict__ kw, const float* __restrict__ kb,
                     const float* __restrict__ q, float* __restrict__ wq){
  __shared__ float sh[4];
  int d = blockIdx.x, t = threadIdx.x;
  const float* row = (d < DQ) ? (kw + (size_t)d*DQ) : kb;
  float s = 0.f;
  for (int e=t;e<DQ;e+=256) s += row[e]*q[e];
  #pragma unroll
  for (int o=32;o;o>>=1) s += __shfl_down(s,o);
  if ((t&63)==0) sh[t>>6]=s;
  __syncthreads();
  if (t==0) wq[d] = sh[0]+sh[1]+sh[2]+sh[3];
}

// ---- mask dtype detector: 0=int32(0/1), 1=float32(0/1.0f), 2=byte(bool)
__global__ void k_det(const unsigned int* __restrict__ m, int* __restrict__ flag){
  __shared__ int so, sf;
  int t = threadIdx.x;
  if (t==0){ so=0; sf=0; }
  __syncthreads();
  int o=0, f1=0;
  for (int i=t;i<MQ/4;i+=256){
    unsigned v = m[i];
    if (v==0x3F800000u) f1=1;
    else if (v>1u) o=1;
  }
  if (o) atomicOr(&so,1);
  if (f1) atomicOr(&sf,1);
  __syncthreads();
  if (t==0) *flag = so?2:(sf?1:0);
}

// ---- fused MFMA GEMM: h=x@W1 (bf16, LDS double-buffered), epilogue GELU·w2
// partials -> gpart[8][M]; xq = x·wq fused into the A staging (f32 precision).
// 128x128 tile, BK=32, 256 threads = 4 waves (2 wm x 2 wn), wave tile 64x64.
__global__ __launch_bounds__(256) void k_gate(
    const float* __restrict__ x, const short* __restrict__ w1t,
    const float* __restrict__ wq, const float* __restrict__ w2,
    const float* __restrict__ b1,
    float* __restrict__ gpart, float* __restrict__ xq)
{
  __shared__ __align__(16) short As[2][BM*BK];   // 8KB x2
  __shared__ __align__(16) short Bs[2][BN*BK];   // 8KB x2
  __shared__ float wqs[DQ];                       // 4KB

  int tid = threadIdx.x;
  int bid = blockIdx.x;
  int bm = bid >> 2, bn = bid & 3;
  int m0 = bm*BM;
  int lane = tid & 63, wid = tid >> 6;
  int wm = wid >> 1, wn = wid & 1;
  int lo = lane & 15, hi = lane >> 4;

  wqs[tid]     = wq[tid];
  wqs[tid+256] = wq[tid+256];
  wqs[tid+512] = wq[tid+512];
  wqs[tid+768] = wq[tid+768];

  // A staging map: thread t -> row t>>1 (0..127), cols (t&1)*16 .. +16
  int ar = tid >> 1, ac = (tid & 1) * 16;
  const float* asrc = x + (size_t)(m0 + ar)*DQ + ac;
  // B staging map: issue i covers tile rows i*64+(t>>2); LDS shorts i*2048 + t*8
  const short* bsrc = w1t + (size_t)(bn*BN + (tid>>2))*DQ + (tid&3)*8;

  float w2v[4], b1v[4];
  #pragma unroll
  for (int fn=0;fn<4;fn++){
    int n = bn*BN + wn*64 + fn*16 + lo;
    w2v[fn] = w2[n]; b1v[fn] = b1[n];
  }

  // ---- prologue: stage k0=0
  f32x4 r0 = *(const f32x4*)(asrc);
  f32x4 r1 = *(const f32x4*)(asrc + 4);
  f32x4 r2 = *(const f32x4*)(asrc + 8);
  f32x4 r3 = *(const f32x4*)(asrc + 12);
  gload_lds16(bsrc,                   &Bs[0][tid*8]);
  gload_lds16(bsrc + (size_t)64*DQ,   &Bs[0][tid*8 + 2048]);
  __syncthreads();   // wqs visible; Bs[0] drained (barrier implies vmcnt(0))
  float xqacc = 0.f;
  {
    f32x4 w0 = *(const f32x4*)(wqs + ac);
    f32x4 w1v = *(const f32x4*)(wqs + ac + 4);
    f32x4 w2q = *(const f32x4*)(wqs + ac + 8);
    f32x4 w3 = *(const f32x4*)(wqs + ac + 12);
    #pragma unroll
    for (int j=0;j<4;j++)
      xqacc += r0[j]*w0[j] + r1[j]*w1v[j] + r2[j]*w2q[j] + r3[j]*w3[j];
    bf16x8 s0, s1;
    #pragma unroll
    for (int j=0;j<4;j++){ s0[j]=f2bf(r0[j]); s0[4+j]=f2bf(r1[j]);
                           s1[j]=f2bf(r2[j]); s1[4+j]=f2bf(r3[j]); }
    *(bf16x8*)(&As[0][ar*BK + ac])     = s0;
    *(bf16x8*)(&As[0][ar*BK + ac + 8]) = s1;
  }
  __syncthreads();

  f32x4 acc[4][4];
  #pragma unroll
  for (int a=0;a<4;a++)
    #pragma unroll
    for (int b=0;b<4;b++) acc[a][b] = (f32x4){0.f,0.f,0.f,0.f};

  for (int t=0;t<32;t++){
    int cur = t & 1, nxt = cur ^ 1;
    int k0n = (t+1)*BK;
    if (t < 31){
      r0 = *(const f32x4*)(asrc + k0n);
      r1 = *(const f32x4*)(asrc + k0n + 4);
      r2 = *(const f32x4*)(asrc + k0n + 8);
      r3 = *(const f32x4*)(asrc + k0n + 12);
      gload_lds16(bsrc + k0n,                 &Bs[nxt][tid*8]);
      gload_lds16(bsrc + (size_t)64*DQ + k0n, &Bs[nxt][tid*8 + 2048]);
    }
    bf16x8 af[4], bfr[4];
    #pragma unroll
    for (int fm=0;fm<4;fm++)
      af[fm] = *(const bf16x8*)(&As[cur][(wm*64+fm*16+lo)*BK + hi*8]);
    #pragma unroll
    for (int fn=0;fn<4;fn++)
      bfr[fn] = *(const bf16x8*)(&Bs[cur][(wn*64+fn*16+lo)*BK + hi*8]);
    #pragma unroll
    for (int fm=0;fm<4;fm++)
      #pragma unroll
      for (int fn=0;fn<4;fn++)
        acc[fm][fn] = __builtin_amdgcn_mfma_f32_16x16x32_bf16(af[fm], bfr[fn], acc[fm][fn], 0,0,0);
    if (t < 31){
      f32x4 w0 = *(const f32x4*)(wqs + k0n + ac);
      f32x4 w1v = *(const f32x4*)(wqs + k0n + ac + 4);
      f32x4 w2q = *(const f32x4*)(wqs + k0n + ac + 8);
      f32x4 w3 = *(const f32x4*)(wqs + k0n + ac + 12);
      #pragma unroll
      for (int j=0;j<4;j++)
        xqacc += r0[j]*w0[j] + r1[j]*w1v[j] + r2[j]*w2q[j] + r3[j]*w3[j];
      bf16x8 s0, s1;
      #pragma unroll
      for (int j=0;j<4;j++){ s0[j]=f2bf(r0[j]); s0[4+j]=f2bf(r1[j]);
                             s1[j]=f2bf(r2[j]); s1[4+j]=f2bf(r3[j]); }
      *(bf16x8*)(&As[nxt][ar*BK + ac])     = s0;
      *(bf16x8*)(&As[nxt][ar*BK + ac + 8]) = s1;
    }
    __syncthreads();
  }

  // xq: combine the 2 threads per row (t and t^1)
  {
    float s = xqacc;
    s += __shfl_xor(s, 1);
    if ((tid & 1) == 0 && bn == 0) xq[m0 + ar] = s;
  }

  // epilogue: GELU + dot w2 over this wave's 64 cols -> per-row partial
  #pragma unroll
  for (int fm=0;fm<4;fm++){
    #pragma unroll
    for (int j=0;j<4;j++){
      float s = 0.f;
      #pragma unroll
      for (int fn=0;fn<4;fn++){
        float h = acc[fm][fn][j] + b1v[fn];
        float g = 0.5f*h*(1.0f + erff(h*0.70710678118f));
        s += g*w2v[fn];
      }
      s += __shfl_xor(s,1); s += __shfl_xor(s,2);
      s += __shfl_xor(s,4); s += __shfl_xor(s,8);
      if (lo == 0){
        int p = bn*2 + wn;
        gpart[(size_t)p*MQ + m0 + wm*64 + fm*16 + hi*4 + j] = s;
      }
    }
  }
}

// ---- per-batch masked softmax with decay; gate=sigmoid(sum gparts + b2)
__device__ __forceinline__ float bredsum(float v, float* sh){
  #pragma unroll
  for (int o=32;o;o>>=1) v += __shfl_down(v,o);
  __syncthreads();
  if ((threadIdx.x&63)==0) sh[threadIdx.x>>6]=v;
  __syncthreads();
  return sh[0]+sh[1]+sh[2]+sh[3];
}
__device__ __forceinline__ float bredmax(float v, float* sh){
  #pragma unroll
  for (int o=32;o;o>>=1) v = fmaxf(v,__shfl_down(v,o));
  __syncthreads();
  if ((threadIdx.x&63)==0) sh[threadIdx.x>>6]=v;
  __syncthreads();
  return fmaxf(fmaxf(sh[0],sh[1]),fmaxf(sh[2],sh[3]));
}

__global__ __launch_bounds__(256) void k_soft(
    const void* __restrict__ maskp, const int* __restrict__ flag,
    const float* __restrict__ gpart, const float* __restrict__ xqv,
    const float* __restrict__ wq, const float* __restrict__ lamp,
    const float* __restrict__ b2, float* __restrict__ wgt)
{
  __shared__ float sh[4];
  int b = blockIdx.x, t = threadIdx.x;
  int fl = *flag;
  const unsigned char* m8 = (const unsigned char*)maskp;
  const float* mf = (const float*)maskp;
  const int* mi = (const int*)maskp;
  size_t base = (size_t)b*SQ;
  int cnt = 0;
  int msk[8];
  #pragma unroll
  for (int i=0;i<8;i++){
    int s = t + i*256;
    size_t idx = base + s;
    int mm = (fl==2) ? (m8[idx]!=0) : (fl==1) ? (mf[idx]!=0.0f) : (mi[idx]!=0);
    msk[i]=mm; cnt += mm^1;
  }
  float L = bredsum((float)cnt, sh);
  float qb = wq[DQ];
  float lam = lamp[0];
  float posl = fmaxf(lam,0.f) + log1pf(expf(-fabsf(lam)));
  const float inv = 0.03125f; // 1/sqrt(1024)
  float dec[8], gt[8];
  float mx = -3.0e38f;
  float b2v = b2[0];
  #pragma unroll
  for (int i=0;i<8;i++){
    int s = t + i*256;
    size_t r = base + s;
    float gsum = b2v;
    #pragma unroll
    for (int p=0;p<8;p++) gsum += gpart[(size_t)p*MQ + r];
    float gate = 1.0f/(1.0f+expf(-gsum));
    gt[i] = gate;
    float lg = (gate*xqv[r] + qb)*inv;
    float pen = fmaxf(L - 1.0f - (float)s, 0.0f);
    float d = lg - posl*pen;
    if (msk[i]) d = -10000.0f;
    dec[i]=d; mx = fmaxf(mx,d);
  }
  mx = bredmax(mx, sh);
  float ssum = 0.f;
  #pragma unroll
  for (int i=0;i<8;i++){ dec[i] = expf(dec[i]-mx); ssum += dec[i]; }
  ssum = bredsum(ssum, sh);
  float rinv = 1.0f/ssum;
  #pragma unroll
  for (int i=0;i<8;i++){
    size_t r = base + t + i*256;
    wgt[r] = dec[i]*rinv*gt[i];
  }
}

// ---- weighted pooling: partials over S chunks
__global__ __launch_bounds__(256) void k_pool(
    const float* __restrict__ x, const float* __restrict__ wgt,
    float* __restrict__ part)
{
  int b = blockIdx.x, sc = blockIdx.y, t = threadIdx.x;
  const int SCH = SQ/SS; // 128
  const float* xb = x + ((size_t)b*SQ + (size_t)sc*SCH)*DQ + t*4;
  const float* wb = wgt + (size_t)b*SQ + (size_t)sc*SCH;
  f32x4 a = {0.f,0.f,0.f,0.f};
  #pragma unroll 4
  for (int s=0;s<SCH;s++){
    float w = wb[s];
    f32x4 v = *(const f32x4*)(xb + (size_t)s*DQ);
    a[0] += w*v[0]; a[1] += w*v[1]; a[2] += w*v[2]; a[3] += w*v[3];
  }
  *(f32x4*)(part + ((size_t)sc*BQ + b)*DQ + t*4) = a;
}

__global__ __launch_bounds__(256) void k_fin(const float* __restrict__ part, float* __restrict__ out){
  int i = blockIdx.x*256 + threadIdx.x;
  float s = 0.f;
  #pragma unroll
  for (int c=0;c<SS;c++) s += part[(size_t)c*(BQ*DQ) + i];
  out[i]=s;
}

extern "C" void kernel_launch(void* const* d_in, const int* in_sizes, int n_in,
                              void* d_out, int out_size, void* d_ws, size_t ws_size,
                              hipStream_t stream)
{
  const float* x    = (const float*)d_in[0];
  const void*  mask = d_in[1];
  const float* w1   = (const float*)d_in[2];
  const float* b1   = (const float*)d_in[3];
  const float* w2   = (const float*)d_in[4];
  const float* b2   = (const float*)d_in[5];
  const float* lam  = (const float*)d_in[6];
  const float* q    = (const float*)d_in[7];
  const float* kw   = (const float*)d_in[8];
  const float* kb   = (const float*)d_in[9];
  char* ws = (char*)d_ws;
  short* w1t = (short*)ws;                               // 1 MB
  float* wq  = (float*)(ws + (1<<20));                   // 8 KB (1025 floats)
  int* flag  = (int*)(ws + (1<<20) + 8192);              // 256 B
  float* gpart = (float*)(ws + (1<<20) + 16384);         // 8 x 256 KB = 2 MB
  float* xq  = gpart + 8*MQ;                             // 256 KB
  float* wgt = xq + MQ;                                  // 256 KB
  float* part= wgt + MQ;                                 // 2 MB
  float* out = (float*)d_out;

  k_w1t<<<dim3((NQ*DQ+255)/256), 256, 0, stream>>>(w1, w1t);
  k_wq<<<dim3(DQ+1), 256, 0, stream>>>(kw, kb, q, wq);
  k_det<<<dim3(1), 256, 0, stream>>>((const unsigned int*)mask, flag);
  k_gate<<<dim3((MQ/BM)*4), 256, 0, stream>>>(x, w1t, wq, w2, b1, gpart, xq);
  k_soft<<<dim3(BQ), 256, 0, stream>>>(mask, flag, gpart, xq, wq, lam, b2, wgt);
  k_pool<<<dim3(BQ, SS), 256, 0, stream>>>(x, wgt, part);
  k_fin<<<dim3((BQ*DQ)/256), 256, 0, stream>>>(part, out);
}

// Round 4
// 245.654 us; speedup vs baseline: 1.8517x; 1.3310x over previous
//
#include <hip/hip_runtime.h>
#include <hip/hip_bf16.h>
#include <math.h>

#define BQ 32
#define SQ 2048
#define DQ 1024
#define NQ 512
#define MQ (BQ*SQ)
#define SS 16
#define BM 128
#define BN 128
#define BK 32

typedef __attribute__((ext_vector_type(8))) short bf16x8;
typedef __attribute__((ext_vector_type(4))) float f32x4;

// compiler-path f32->bf16 (RTNE, emits v_cvt_pk_bf16_f32 when paired)
__device__ __forceinline__ short f2bf(float f){
  return __builtin_bit_cast(short, __float2bfloat16(f));
}

__device__ __forceinline__ void gload_lds16(const void* g, void* l){
  __builtin_amdgcn_global_load_lds(
      (const __attribute__((address_space(1))) unsigned int*)g,
      (__attribute__((address_space(3))) unsigned int*)l, 16, 0, 0);
}

// ---- prep: transpose gate_w1 [K=1024][N=512] -> bf16 w1t [N=512][K=1024]
__global__ void k_w1t(const float* __restrict__ w1, short* __restrict__ w1t){
  int i = blockIdx.x*256 + threadIdx.x;
  if (i >= NQ*DQ) return;
  int n = i >> 10, k = i & (DQ-1);
  w1t[i] = f2bf(w1[(size_t)k*NQ + n]);
}

// ---- prep: wq[d] = key_w[d,:]·q (d<1024); wq[1024] = key_b·q
__global__ void k_wq(const float* __restrict__ kw, const float* __restrict__ kb,
                     const float* __restrict__ q, float* __restrict__ wq){
  __shared__ float sh[4];
  int d = blockIdx.x, t = threadIdx.x;
  const float* row = (d < DQ) ? (kw + (size_t)d*DQ) : kb;
  float s = 0.f;
  for (int e=t;e<DQ;e+=256) s += row[e]*q[e];
  #pragma unroll
  for (int o=32;o;o>>=1) s += __shfl_down(s,o);
  if ((t&63)==0) sh[t>>6]=s;
  __syncthreads();
  if (t==0) wq[d] = sh[0]+sh[1]+sh[2]+sh[3];
}

// ---- mask dtype detector: 0=int32(0/1), 1=float32(0/1.0f), 2=byte(bool)
__global__ void k_det(const unsigned int* __restrict__ m, int* __restrict__ flag){
  __shared__ int so, sf;
  int t = threadIdx.x;
  if (t==0){ so=0; sf=0; }
  __syncthreads();
  int o=0, f1=0;
  for (int i=t;i<MQ/4;i+=256){
    unsigned v = m[i];
    if (v==0x3F800000u) f1=1;
    else if (v>1u) o=1;
  }
  if (o) atomicOr(&so,1);
  if (f1) atomicOr(&sf,1);
  __syncthreads();
  if (t==0) *flag = so?2:(sf?1:0);
}

// ---- fused MFMA GEMM: h=x@W1 (bf16, LDS double-buffered), epilogue GELU·w2
// partials -> gpart[8][M]; xq = x·wq fused into the A staging (bn==0 only).
// 128x128 tile, BK=32, 256 threads = 4 waves (2 wm x 2 wn), wave tile 64x64.
// Chunked XCD remap: the 4 bn-blocks of each bm land on one XCD's L2.
__global__ __launch_bounds__(256) void k_gate(
    const float* __restrict__ x, const short* __restrict__ w1t,
    const float* __restrict__ wq, const float* __restrict__ w2,
    const float* __restrict__ b1,
    float* __restrict__ gpart, float* __restrict__ xq)
{
  __shared__ __align__(16) short As[2][BM*BK];   // 8KB x2
  __shared__ __align__(16) short Bs[2][BN*BK];   // 8KB x2
  __shared__ float wqs[DQ];                       // 4KB

  int tid = threadIdx.x;
  int phys = blockIdx.x;
  // 2048 blocks, 8 XCDs round-robin by phys%8 -> logical chunks of 256/XCD
  int bid = ((phys & 7) << 8) | (phys >> 3);
  int bm = bid >> 2, bn = bid & 3;
  int m0 = bm*BM;
  int lane = tid & 63, wid = tid >> 6;
  int wm = wid >> 1, wn = wid & 1;
  int lo = lane & 15, hi = lane >> 4;

  wqs[tid]     = wq[tid];
  wqs[tid+256] = wq[tid+256];
  wqs[tid+512] = wq[tid+512];
  wqs[tid+768] = wq[tid+768];

  // A staging map: thread t -> row t>>1 (0..127), cols (t&1)*16 .. +16
  int ar = tid >> 1, ac = (tid & 1) * 16;
  const float* asrc = x + (size_t)(m0 + ar)*DQ + ac;
  // B staging map: issue i covers tile rows i*64+(t>>2); LDS shorts i*2048 + t*8
  const short* bsrc = w1t + (size_t)(bn*BN + (tid>>2))*DQ + (tid&3)*8;

  float w2v[4], b1v[4];
  #pragma unroll
  for (int fn=0;fn<4;fn++){
    int n = bn*BN + wn*64 + fn*16 + lo;
    w2v[fn] = w2[n]; b1v[fn] = b1[n];
  }

  // ---- prologue: stage k0=0
  f32x4 r0 = *(const f32x4*)(asrc);
  f32x4 r1 = *(const f32x4*)(asrc + 4);
  f32x4 r2 = *(const f32x4*)(asrc + 8);
  f32x4 r3 = *(const f32x4*)(asrc + 12);
  gload_lds16(bsrc,                   &Bs[0][tid*8]);
  gload_lds16(bsrc + (size_t)64*DQ,   &Bs[0][tid*8 + 2048]);
  __syncthreads();   // wqs visible; Bs[0] drained (barrier implies vmcnt(0))
  float xqacc = 0.f;
  {
    if (bn == 0){
      f32x4 w0 = *(const f32x4*)(wqs + ac);
      f32x4 w1v = *(const f32x4*)(wqs + ac + 4);
      f32x4 w2q = *(const f32x4*)(wqs + ac + 8);
      f32x4 w3 = *(const f32x4*)(wqs + ac + 12);
      #pragma unroll
      for (int j=0;j<4;j++)
        xqacc += r0[j]*w0[j] + r1[j]*w1v[j] + r2[j]*w2q[j] + r3[j]*w3[j];
    }
    bf16x8 s0, s1;
    #pragma unroll
    for (int j=0;j<4;j++){ s0[j]=f2bf(r0[j]); s0[4+j]=f2bf(r1[j]);
                           s1[j]=f2bf(r2[j]); s1[4+j]=f2bf(r3[j]); }
    *(bf16x8*)(&As[0][ar*BK + ac])     = s0;
    *(bf16x8*)(&As[0][ar*BK + ac + 8]) = s1;
  }
  __syncthreads();

  f32x4 acc[4][4];
  #pragma unroll
  for (int a=0;a<4;a++)
    #pragma unroll
    for (int b=0;b<4;b++) acc[a][b] = (f32x4){0.f,0.f,0.f,0.f};

  for (int t=0;t<32;t++){
    int cur = t & 1, nxt = cur ^ 1;
    int k0n = (t+1)*BK;
    if (t < 31){
      r0 = *(const f32x4*)(asrc + k0n);
      r1 = *(const f32x4*)(asrc + k0n + 4);
      r2 = *(const f32x4*)(asrc + k0n + 8);
      r3 = *(const f32x4*)(asrc + k0n + 12);
      gload_lds16(bsrc + k0n,                 &Bs[nxt][tid*8]);
      gload_lds16(bsrc + (size_t)64*DQ + k0n, &Bs[nxt][tid*8 + 2048]);
    }
    bf16x8 af[4], bfr[4];
    #pragma unroll
    for (int fm=0;fm<4;fm++)
      af[fm] = *(const bf16x8*)(&As[cur][(wm*64+fm*16+lo)*BK + hi*8]);
    #pragma unroll
    for (int fn=0;fn<4;fn++)
      bfr[fn] = *(const bf16x8*)(&Bs[cur][(wn*64+fn*16+lo)*BK + hi*8]);
    #pragma unroll
    for (int fm=0;fm<4;fm++)
      #pragma unroll
      for (int fn=0;fn<4;fn++)
        acc[fm][fn] = __builtin_amdgcn_mfma_f32_16x16x32_bf16(af[fm], bfr[fn], acc[fm][fn], 0,0,0);
    if (t < 31){
      if (bn == 0){
        f32x4 w0 = *(const f32x4*)(wqs + k0n + ac);
        f32x4 w1v = *(const f32x4*)(wqs + k0n + ac + 4);
        f32x4 w2q = *(const f32x4*)(wqs + k0n + ac + 8);
        f32x4 w3 = *(const f32x4*)(wqs + k0n + ac + 12);
        #pragma unroll
        for (int j=0;j<4;j++)
          xqacc += r0[j]*w0[j] + r1[j]*w1v[j] + r2[j]*w2q[j] + r3[j]*w3[j];
      }
      bf16x8 s0, s1;
      #pragma unroll
      for (int j=0;j<4;j++){ s0[j]=f2bf(r0[j]); s0[4+j]=f2bf(r1[j]);
                             s1[j]=f2bf(r2[j]); s1[4+j]=f2bf(r3[j]); }
      *(bf16x8*)(&As[nxt][ar*BK + ac])     = s0;
      *(bf16x8*)(&As[nxt][ar*BK + ac + 8]) = s1;
    }
    __syncthreads();
  }

  // xq: combine the 2 threads per row (t and t^1)
  if (bn == 0){
    float s = xqacc;
    s += __shfl_xor(s, 1);
    if ((tid & 1) == 0) xq[m0 + ar] = s;
  }

  // epilogue: GELU + dot w2 over this wave's 64 cols -> per-row partial
  #pragma unroll
  for (int fm=0;fm<4;fm++){
    #pragma unroll
    for (int j=0;j<4;j++){
      float s = 0.f;
      #pragma unroll
      for (int fn=0;fn<4;fn++){
        float h = acc[fm][fn][j] + b1v[fn];
        float g = 0.5f*h*(1.0f + erff(h*0.70710678118f));
        s += g*w2v[fn];
      }
      s += __shfl_xor(s,1); s += __shfl_xor(s,2);
      s += __shfl_xor(s,4); s += __shfl_xor(s,8);
      if (lo == 0){
        int p = bn*2 + wn;
        gpart[(size_t)p*MQ + m0 + wm*64 + fm*16 + hi*4 + j] = s;
      }
    }
  }
}

// ---- per-batch masked softmax with decay; gate=sigmoid(sum gparts + b2)
__device__ __forceinline__ float bredsum(float v, float* sh){
  #pragma unroll
  for (int o=32;o;o>>=1) v += __shfl_down(v,o);
  __syncthreads();
  if ((threadIdx.x&63)==0) sh[threadIdx.x>>6]=v;
  __syncthreads();
  return sh[0]+sh[1]+sh[2]+sh[3];
}
__device__ __forceinline__ float bredmax(float v, float* sh){
  #pragma unroll
  for (int o=32;o;o>>=1) v = fmaxf(v,__shfl_down(v,o));
  __syncthreads();
  if ((threadIdx.x&63)==0) sh[threadIdx.x>>6]=v;
  __syncthreads();
  return fmaxf(fmaxf(sh[0],sh[1]),fmaxf(sh[2],sh[3]));
}

__global__ __launch_bounds__(256) void k_soft(
    const void* __restrict__ maskp, const int* __restrict__ flag,
    const float* __restrict__ gpart, const float* __restrict__ xqv,
    const float* __restrict__ wq, const float* __restrict__ lamp,
    const float* __restrict__ b2, float* __restrict__ wgt)
{
  __shared__ float sh[4];
  int b = blockIdx.x, t = threadIdx.x;
  int fl = *flag;
  const unsigned char* m8 = (const unsigned char*)maskp;
  const float* mf = (const float*)maskp;
  const int* mi = (const int*)maskp;
  size_t base = (size_t)b*SQ;
  int cnt = 0;
  int msk[8];
  #pragma unroll
  for (int i=0;i<8;i++){
    int s = t + i*256;
    size_t idx = base + s;
    int mm = (fl==2) ? (m8[idx]!=0) : (fl==1) ? (mf[idx]!=0.0f) : (mi[idx]!=0);
    msk[i]=mm; cnt += mm^1;
  }
  float L = bredsum((float)cnt, sh);
  float qb = wq[DQ];
  float lam = lamp[0];
  float posl = fmaxf(lam,0.f) + log1pf(expf(-fabsf(lam)));
  const float inv = 0.03125f; // 1/sqrt(1024)
  float dec[8], gt[8];
  float mx = -3.0e38f;
  float b2v = b2[0];
  #pragma unroll
  for (int i=0;i<8;i++){
    int s = t + i*256;
    size_t r = base + s;
    float gsum = b2v;
    #pragma unroll
    for (int p=0;p<8;p++) gsum += gpart[(size_t)p*MQ + r];
    float gate = 1.0f/(1.0f+expf(-gsum));
    gt[i] = gate;
    float lg = (gate*xqv[r] + qb)*inv;
    float pen = fmaxf(L - 1.0f - (float)s, 0.0f);
    float d = lg - posl*pen;
    if (msk[i]) d = -10000.0f;
    dec[i]=d; mx = fmaxf(mx,d);
  }
  mx = bredmax(mx, sh);
  float ssum = 0.f;
  #pragma unroll
  for (int i=0;i<8;i++){ dec[i] = expf(dec[i]-mx); ssum += dec[i]; }
  ssum = bredsum(ssum, sh);
  float rinv = 1.0f/ssum;
  #pragma unroll
  for (int i=0;i<8;i++){
    size_t r = base + t + i*256;
    wgt[r] = dec[i]*rinv*gt[i];
  }
}

// ---- weighted pooling: partials over S chunks
__global__ __launch_bounds__(256) void k_pool(
    const float* __restrict__ x, const float* __restrict__ wgt,
    float* __restrict__ part)
{
  int b = blockIdx.x, sc = blockIdx.y, t = threadIdx.x;
  const int SCH = SQ/SS; // 128
  const float* xb = x + ((size_t)b*SQ + (size_t)sc*SCH)*DQ + t*4;
  const float* wb = wgt + (size_t)b*SQ + (size_t)sc*SCH;
  f32x4 a = {0.f,0.f,0.f,0.f};
  #pragma unroll 4
  for (int s=0;s<SCH;s++){
    float w = wb[s];
    f32x4 v = *(const f32x4*)(xb + (size_t)s*DQ);
    a[0] += w*v[0]; a[1] += w*v[1]; a[2] += w*v[2]; a[3] += w*v[3];
  }
  *(f32x4*)(part + ((size_t)sc*BQ + b)*DQ + t*4) = a;
}

__global__ __launch_bounds__(256) void k_fin(const float* __restrict__ part, float* __restrict__ out){
  int i = blockIdx.x*256 + threadIdx.x;
  float s = 0.f;
  #pragma unroll
  for (int c=0;c<SS;c++) s += part[(size_t)c*(BQ*DQ) + i];
  out[i]=s;
}

extern "C" void kernel_launch(void* const* d_in, const int* in_sizes, int n_in,
                              void* d_out, int out_size, void* d_ws, size_t ws_size,
                              hipStream_t stream)
{
  const float* x    = (const float*)d_in[0];
  const void*  mask = d_in[1];
  const float* w1   = (const float*)d_in[2];
  const float* b1   = (const float*)d_in[3];
  const float* w2   = (const float*)d_in[4];
  const float* b2   = (const float*)d_in[5];
  const float* lam  = (const float*)d_in[6];
  const float* q    = (const float*)d_in[7];
  const float* kw   = (const float*)d_in[8];
  const float* kb   = (const float*)d_in[9];
  char* ws = (char*)d_ws;
  short* w1t = (short*)ws;                               // 1 MB
  float* wq  = (float*)(ws + (1<<20));                   // 8 KB (1025 floats)
  int* flag  = (int*)(ws + (1<<20) + 8192);              // 256 B
  float* gpart = (float*)(ws + (1<<20) + 16384);         // 8 x 256 KB = 2 MB
  float* xq  = gpart + 8*MQ;                             // 256 KB
  float* wgt = xq + MQ;                                  // 256 KB
  float* part= wgt + MQ;                                 // 2 MB
  float* out = (float*)d_out;

  k_w1t<<<dim3((NQ*DQ+255)/256), 256, 0, stream>>>(w1, w1t);
  k_wq<<<dim3(DQ+1), 256, 0, stream>>>(kw, kb, q, wq);
  k_det<<<dim3(1), 256, 0, stream>>>((const unsigned int*)mask, flag);
  k_gate<<<dim3((MQ/BM)*4), 256, 0, stream>>>(x, w1t, wq, w2, b1, gpart, xq);
  k_soft<<<dim3(BQ), 256, 0, stream>>>(mask, flag, gpart, xq, wq, lam, b2, wgt);
  k_pool<<<dim3(BQ, SS), 256, 0, stream>>>(x, wgt, part);
  k_fin<<<dim3((BQ*DQ)/256), 256, 0, stream>>>(part, out);
}

// Round 5
// 197.371 us; speedup vs baseline: 2.3047x; 1.2446x over previous
//
#include <hip/hip_runtime.h>
#include <hip/hip_bf16.h>
#include <math.h>

#define BQ 32
#define SQ 2048
#define DQ 1024
#define NQ 512
#define MQ (BQ*SQ)
#define SS 16
#define BM 128
#define BN 256
#define BK 32

typedef __attribute__((ext_vector_type(8))) short bf16x8;
typedef __attribute__((ext_vector_type(4))) float f32x4;

// compiler-path f32->bf16 (RTNE, pairs into v_cvt_pk_bf16_f32)
__device__ __forceinline__ short f2bf(float f){
  return __builtin_bit_cast(short, __float2bfloat16(f));
}

__device__ __forceinline__ void gload_lds16(const void* g, void* l){
  __builtin_amdgcn_global_load_lds(
      (const __attribute__((address_space(1))) unsigned int*)g,
      (__attribute__((address_space(3))) unsigned int*)l, 16, 0, 0);
}

// ---- prep: transpose gate_w1 [K=1024][N=512] -> bf16 w1t [N=512][K=1024]
__global__ void k_w1t(const float* __restrict__ w1, short* __restrict__ w1t){
  int i = blockIdx.x*256 + threadIdx.x;
  if (i >= NQ*DQ) return;
  int n = i >> 10, k = i & (DQ-1);
  w1t[i] = f2bf(w1[(size_t)k*NQ + n]);
}

// ---- prep: wq[d] = key_w[d,:]·q (d<1024); wq[1024] = key_b·q
__global__ void k_wq(const float* __restrict__ kw, const float* __restrict__ kb,
                     const float* __restrict__ q, float* __restrict__ wq){
  __shared__ float sh[4];
  int d = blockIdx.x, t = threadIdx.x;
  const float* row = (d < DQ) ? (kw + (size_t)d*DQ) : kb;
  float s = 0.f;
  for (int e=t;e<DQ;e+=256) s += row[e]*q[e];
  #pragma unroll
  for (int o=32;o;o>>=1) s += __shfl_down(s,o);
  if ((t&63)==0) sh[t>>6]=s;
  __syncthreads();
  if (t==0) wq[d] = sh[0]+sh[1]+sh[2]+sh[3];
}

// ---- mask dtype detector: 0=int32(0/1), 1=float32(0/1.0f), 2=byte(bool)
__global__ void k_det(const unsigned int* __restrict__ m, int* __restrict__ flag){
  __shared__ int so, sf;
  int t = threadIdx.x;
  if (t==0){ so=0; sf=0; }
  __syncthreads();
  int o=0, f1=0;
  for (int i=t;i<MQ/4;i+=256){
    unsigned v = m[i];
    if (v==0x3F800000u) f1=1;
    else if (v>1u) o=1;
  }
  if (o) atomicOr(&so,1);
  if (f1) atomicOr(&sf,1);
  __syncthreads();
  if (t==0) *flag = so?2:(sf?1:0);
}

// ---- fused MFMA GEMM: h=x@W1 (bf16, LDS double-buffered), epilogue GELU·w2
// partials -> gpart[8][M]; xq = x·wq fused into A staging (bn==0 blocks only).
// 128x256 tile, BK=32, 512 threads = 8 waves (2 wm x 4 wn), wave tile 64x64.
// Chunked XCD remap: both bn-blocks of each bm land on one XCD's L2.
__global__ __launch_bounds__(512) void k_gate(
    const float* __restrict__ x, const short* __restrict__ w1t,
    const float* __restrict__ wq, const float* __restrict__ w2,
    const float* __restrict__ b1,
    float* __restrict__ gpart, float* __restrict__ xq)
{
  __shared__ __align__(16) short As[2][BM*BK];   // 8KB x2
  __shared__ __align__(16) short Bs[2][BN*BK];   // 16KB x2
  __shared__ float wqs[DQ];                       // 4KB

  int tid = threadIdx.x;
  int phys = blockIdx.x;
  // 1024 blocks, 8 XCDs round-robin by phys%8 -> logical chunks of 128/XCD
  int bid = ((phys & 7) << 7) | (phys >> 3);
  int bm = bid >> 1, bn = bid & 1;
  int m0 = bm*BM;
  int lane = tid & 63, wid = tid >> 6;
  int wm = wid >> 2, wn = wid & 3;
  int lo = lane & 15, hi = lane >> 4;

  wqs[tid]     = wq[tid];
  wqs[tid+512] = wq[tid+512];

  // A staging map: thread t -> row t>>2 (0..127), cols (t&3)*8 .. +8
  int ar = tid >> 2, ac = (tid & 3) * 8;
  const float* asrc = x + (size_t)(m0 + ar)*DQ + ac;
  // B staging: issue i covers tile rows i*128+(t>>2); LDS shorts i*4096 + t*8
  const short* bsrc = w1t + (size_t)(bn*BN + (tid>>2))*DQ + (tid&3)*8;

  float w2v[4], b1v[4];
  #pragma unroll
  for (int fn=0;fn<4;fn++){
    int n = bn*BN + wn*64 + fn*16 + lo;
    w2v[fn] = w2[n]; b1v[fn] = b1[n];
  }

  // ---- prologue: stage k0=0
  f32x4 r0 = *(const f32x4*)(asrc);
  f32x4 r1 = *(const f32x4*)(asrc + 4);
  gload_lds16(bsrc,                    &Bs[0][tid*8]);
  gload_lds16(bsrc + (size_t)128*DQ,   &Bs[0][tid*8 + 4096]);
  __syncthreads();   // wqs visible; Bs[0] drained (barrier implies vmcnt(0))
  float xqacc = 0.f;
  {
    if (bn == 0){
      f32x4 w0 = *(const f32x4*)(wqs + ac);
      f32x4 w1v = *(const f32x4*)(wqs + ac + 4);
      #pragma unroll
      for (int j=0;j<4;j++)
        xqacc += r0[j]*w0[j] + r1[j]*w1v[j];
    }
    bf16x8 s0;
    #pragma unroll
    for (int j=0;j<4;j++){ s0[j]=f2bf(r0[j]); s0[4+j]=f2bf(r1[j]); }
    *(bf16x8*)(&As[0][ar*BK + ac]) = s0;
  }
  __syncthreads();

  f32x4 acc[4][4];
  #pragma unroll
  for (int a=0;a<4;a++)
    #pragma unroll
    for (int b=0;b<4;b++) acc[a][b] = (f32x4){0.f,0.f,0.f,0.f};

  for (int t=0;t<32;t++){
    int cur = t & 1, nxt = cur ^ 1;
    int k0n = (t+1)*BK;
    if (t < 31){
      r0 = *(const f32x4*)(asrc + k0n);
      r1 = *(const f32x4*)(asrc + k0n + 4);
      gload_lds16(bsrc + k0n,                  &Bs[nxt][tid*8]);
      gload_lds16(bsrc + (size_t)128*DQ + k0n, &Bs[nxt][tid*8 + 4096]);
    }
    bf16x8 af[4], bfr[4];
    #pragma unroll
    for (int fm=0;fm<4;fm++)
      af[fm] = *(const bf16x8*)(&As[cur][(wm*64+fm*16+lo)*BK + hi*8]);
    #pragma unroll
    for (int fn=0;fn<4;fn++)
      bfr[fn] = *(const bf16x8*)(&Bs[cur][(wn*64+fn*16+lo)*BK + hi*8]);
    #pragma unroll
    for (int fm=0;fm<4;fm++)
      #pragma unroll
      for (int fn=0;fn<4;fn++)
        acc[fm][fn] = __builtin_amdgcn_mfma_f32_16x16x32_bf16(af[fm], bfr[fn], acc[fm][fn], 0,0,0);
    if (t < 31){
      if (bn == 0){
        f32x4 w0 = *(const f32x4*)(wqs + k0n + ac);
        f32x4 w1v = *(const f32x4*)(wqs + k0n + ac + 4);
        #pragma unroll
        for (int j=0;j<4;j++)
          xqacc += r0[j]*w0[j] + r1[j]*w1v[j];
      }
      bf16x8 s0;
      #pragma unroll
      for (int j=0;j<4;j++){ s0[j]=f2bf(r0[j]); s0[4+j]=f2bf(r1[j]); }
      *(bf16x8*)(&As[nxt][ar*BK + ac]) = s0;
    }
    __syncthreads();
  }

  // xq: combine the 4 threads per row (t&3)
  if (bn == 0){
    float s = xqacc;
    s += __shfl_xor(s, 1);
    s += __shfl_xor(s, 2);
    if ((tid & 3) == 0) xq[m0 + ar] = s;
  }

  // epilogue: GELU + dot w2 over this wave's 64 cols -> per-row partial
  #pragma unroll
  for (int fm=0;fm<4;fm++){
    #pragma unroll
    for (int j=0;j<4;j++){
      float s = 0.f;
      #pragma unroll
      for (int fn=0;fn<4;fn++){
        float h = acc[fm][fn][j] + b1v[fn];
        float g = 0.5f*h*(1.0f + erff(h*0.70710678118f));
        s += g*w2v[fn];
      }
      s += __shfl_xor(s,1); s += __shfl_xor(s,2);
      s += __shfl_xor(s,4); s += __shfl_xor(s,8);
      if (lo == 0){
        int p = bn*4 + wn;
        gpart[(size_t)p*MQ + m0 + wm*64 + fm*16 + hi*4 + j] = s;
      }
    }
  }
}

// ---- per-batch masked softmax with decay; gate=sigmoid(sum gparts + b2)
__device__ __forceinline__ float bredsum(float v, float* sh){
  #pragma unroll
  for (int o=32;o;o>>=1) v += __shfl_down(v,o);
  __syncthreads();
  if ((threadIdx.x&63)==0) sh[threadIdx.x>>6]=v;
  __syncthreads();
  return sh[0]+sh[1]+sh[2]+sh[3];
}
__device__ __forceinline__ float bredmax(float v, float* sh){
  #pragma unroll
  for (int o=32;o;o>>=1) v = fmaxf(v,__shfl_down(v,o));
  __syncthreads();
  if ((threadIdx.x&63)==0) sh[threadIdx.x>>6]=v;
  __syncthreads();
  return fmaxf(fmaxf(sh[0],sh[1]),fmaxf(sh[2],sh[3]));
}

__global__ __launch_bounds__(256) void k_soft(
    const void* __restrict__ maskp, const int* __restrict__ flag,
    const float* __restrict__ gpart, const float* __restrict__ xqv,
    const float* __restrict__ wq, const float* __restrict__ lamp,
    const float* __restrict__ b2, float* __restrict__ wgt)
{
  __shared__ float sh[4];
  int b = blockIdx.x, t = threadIdx.x;
  int fl = *flag;
  const unsigned char* m8 = (const unsigned char*)maskp;
  const float* mf = (const float*)maskp;
  const int* mi = (const int*)maskp;
  size_t base = (size_t)b*SQ;
  int cnt = 0;
  int msk[8];
  #pragma unroll
  for (int i=0;i<8;i++){
    int s = t + i*256;
    size_t idx = base + s;
    int mm = (fl==2) ? (m8[idx]!=0) : (fl==1) ? (mf[idx]!=0.0f) : (mi[idx]!=0);
    msk[i]=mm; cnt += mm^1;
  }
  float L = bredsum((float)cnt, sh);
  float qb = wq[DQ];
  float lam = lamp[0];
  float posl = fmaxf(lam,0.f) + log1pf(expf(-fabsf(lam)));
  const float inv = 0.03125f; // 1/sqrt(1024)
  float dec[8], gt[8];
  float mx = -3.0e38f;
  float b2v = b2[0];
  #pragma unroll
  for (int i=0;i<8;i++){
    int s = t + i*256;
    size_t r = base + s;
    float gsum = b2v;
    #pragma unroll
    for (int p=0;p<8;p++) gsum += gpart[(size_t)p*MQ + r];
    float gate = 1.0f/(1.0f+expf(-gsum));
    gt[i] = gate;
    float lg = (gate*xqv[r] + qb)*inv;
    float pen = fmaxf(L - 1.0f - (float)s, 0.0f);
    float d = lg - posl*pen;
    if (msk[i]) d = -10000.0f;
    dec[i]=d; mx = fmaxf(mx,d);
  }
  mx = bredmax(mx, sh);
  float ssum = 0.f;
  #pragma unroll
  for (int i=0;i<8;i++){ dec[i] = expf(dec[i]-mx); ssum += dec[i]; }
  ssum = bredsum(ssum, sh);
  float rinv = 1.0f/ssum;
  #pragma unroll
  for (int i=0;i<8;i++){
    size_t r = base + t + i*256;
    wgt[r] = dec[i]*rinv*gt[i];
  }
}

// ---- weighted pooling: partials over S chunks
__global__ __launch_bounds__(256) void k_pool(
    const float* __restrict__ x, const float* __restrict__ wgt,
    float* __restrict__ part)
{
  int b = blockIdx.x, sc = blockIdx.y, t = threadIdx.x;
  const int SCH = SQ/SS; // 128
  const float* xb = x + ((size_t)b*SQ + (size_t)sc*SCH)*DQ + t*4;
  const float* wb = wgt + (size_t)b*SQ + (size_t)sc*SCH;
  f32x4 a = {0.f,0.f,0.f,0.f};
  #pragma unroll 4
  for (int s=0;s<SCH;s++){
    float w = wb[s];
    f32x4 v = *(const f32x4*)(xb + (size_t)s*DQ);
    a[0] += w*v[0]; a[1] += w*v[1]; a[2] += w*v[2]; a[3] += w*v[3];
  }
  *(f32x4*)(part + ((size_t)sc*BQ + b)*DQ + t*4) = a;
}

__global__ __launch_bounds__(256) void k_fin(const float* __restrict__ part, float* __restrict__ out){
  int i = blockIdx.x*256 + threadIdx.x;
  float s = 0.f;
  #pragma unroll
  for (int c=0;c<SS;c++) s += part[(size_t)c*(BQ*DQ) + i];
  out[i]=s;
}

extern "C" void kernel_launch(void* const* d_in, const int* in_sizes, int n_in,
                              void* d_out, int out_size, void* d_ws, size_t ws_size,
                              hipStream_t stream)
{
  const float* x    = (const float*)d_in[0];
  const void*  mask = d_in[1];
  const float* w1   = (const float*)d_in[2];
  const float* b1   = (const float*)d_in[3];
  const float* w2   = (const float*)d_in[4];
  const float* b2   = (const float*)d_in[5];
  const float* lam  = (const float*)d_in[6];
  const float* q    = (const float*)d_in[7];
  const float* kw   = (const float*)d_in[8];
  const float* kb   = (const float*)d_in[9];
  char* ws = (char*)d_ws;
  short* w1t = (short*)ws;                               // 1 MB
  float* wq  = (float*)(ws + (1<<20));                   // 8 KB (1025 floats)
  int* flag  = (int*)(ws + (1<<20) + 8192);              // 256 B
  float* gpart = (float*)(ws + (1<<20) + 16384);         // 8 x 256 KB = 2 MB
  float* xq  = gpart + 8*MQ;                             // 256 KB
  float* wgt = xq + MQ;                                  // 256 KB
  float* part= wgt + MQ;                                 // 2 MB
  float* out = (float*)d_out;

  k_w1t<<<dim3((NQ*DQ+255)/256), 256, 0, stream>>>(w1, w1t);
  k_wq<<<dim3(DQ+1), 256, 0, stream>>>(kw, kb, q, wq);
  k_det<<<dim3(1), 256, 0, stream>>>((const unsigned int*)mask, flag);
  k_gate<<<dim3((MQ/BM)*2), 512, 0, stream>>>(x, w1t, wq, w2, b1, gpart, xq);
  k_soft<<<dim3(BQ), 256, 0, stream>>>(mask, flag, gpart, xq, wq, lam, b2, wgt);
  k_pool<<<dim3(BQ, SS), 256, 0, stream>>>(x, wgt, part);
  k_fin<<<dim3((BQ*DQ)/256), 256, 0, stream>>>(part, out);
}

// Round 7
// 185.319 us; speedup vs baseline: 2.4546x; 1.0650x over previous
//
#include <hip/hip_runtime.h>
#include <hip/hip_bf16.h>
#include <math.h>

#define BQ 32
#define SQ 2048
#define DQ 1024
#define NQ 512
#define MQ (BQ*SQ)
#define BM 64
#define BN 512
#define BK 32

typedef __attribute__((ext_vector_type(8))) short bf16x8;
typedef __attribute__((ext_vector_type(4))) short bf16x4;
typedef __attribute__((ext_vector_type(4))) float f32x4;

// compiler-path f32->bf16 (RTNE, pairs into v_cvt_pk_bf16_f32)
__device__ __forceinline__ short f2bf(float f){
  return __builtin_bit_cast(short, __float2bfloat16(f));
}

__device__ __forceinline__ void gload_lds16(const void* g, void* l){
  __builtin_amdgcn_global_load_lds(
      (const __attribute__((address_space(1))) unsigned int*)g,
      (__attribute__((address_space(3))) unsigned int*)l, 16, 0, 0);
}

// ---- prep: transpose gate_w1 [K=1024][N=512] -> bf16 w1t [N=512][K=1024]
__global__ void k_w1t(const float* __restrict__ w1, short* __restrict__ w1t){
  int i = blockIdx.x*256 + threadIdx.x;
  if (i >= NQ*DQ) return;
  int n = i >> 10, k = i & (DQ-1);
  w1t[i] = f2bf(w1[(size_t)k*NQ + n]);
}

// ---- prep: wq[d] = key_w[d,:]·q (d<1024); wq[1024] = key_b·q
__global__ void k_wq(const float* __restrict__ kw, const float* __restrict__ kb,
                     const float* __restrict__ q, float* __restrict__ wq){
  __shared__ float sh[4];
  int d = blockIdx.x, t = threadIdx.x;
  const float* row = (d < DQ) ? (kw + (size_t)d*DQ) : kb;
  float s = 0.f;
  for (int e=t;e<DQ;e+=256) s += row[e]*q[e];
  #pragma unroll
  for (int o=32;o;o>>=1) s += __shfl_down(s,o);
  if ((t&63)==0) sh[t>>6]=s;
  __syncthreads();
  if (t==0) wq[d] = sh[0]+sh[1]+sh[2]+sh[3];
}

// ---- mask dtype detector: 0=int32(0/1), 1=float32(0/1.0f), 2=byte(bool)
__global__ void k_det(const unsigned int* __restrict__ m, int* __restrict__ flag){
  __shared__ int so, sf;
  int t = threadIdx.x;
  if (t==0){ so=0; sf=0; }
  __syncthreads();
  int o=0, f1=0;
  for (int i=t;i<MQ/4;i+=256){
    unsigned v = m[i];
    if (v==0x3F800000u) f1=1;
    else if (v>1u) o=1;
  }
  if (o) atomicOr(&so,1);
  if (f1) atomicOr(&sf,1);
  __syncthreads();
  if (t==0) *flag = so?2:(sf?1:0);
}

// ---- per-batch valid length (reads flag; stream-ordered after k_det)
__global__ __launch_bounds__(256) void k_len(const void* __restrict__ maskp,
                                             const int* __restrict__ flag,
                                             int* __restrict__ lens){
  __shared__ int sh[4];
  int b = blockIdx.x, t = threadIdx.x;
  int fl = *flag;
  const unsigned char* m8 = (const unsigned char*)maskp;
  const float* mf = (const float*)maskp;
  const int* mi = (const int*)maskp;
  int cnt = 0;
  #pragma unroll
  for (int i=0;i<8;i++){
    size_t idx = (size_t)b*SQ + t + i*256;
    int mm = (fl==2) ? (m8[idx]!=0) : (fl==1) ? (mf[idx]!=0.0f) : (mi[idx]!=0);
    cnt += mm^1;
  }
  #pragma unroll
  for (int o=32;o;o>>=1) cnt += __shfl_down(cnt,o);
  if ((t&63)==0) sh[t>>6]=cnt;
  __syncthreads();
  if (t==0) lens[b] = sh[0]+sh[1]+sh[2]+sh[3];
}

// ---- fused: h=x@W1 (MFMA, LDS dbuf) -> gate -> e=exp(dec), w=e*gate -> partial pool.
// 64x512 tile (full N), BK=32, 512 threads = 8 waves over N, wave tile 64x64.
__global__ __launch_bounds__(512) void k_gate(
    const float* __restrict__ x, const short* __restrict__ w1t,
    const float* __restrict__ wq, const float* __restrict__ w2,
    const float* __restrict__ b1, const float* __restrict__ b2p,
    const float* __restrict__ lamp,
    const void* __restrict__ maskp, const int* __restrict__ flag,
    const int* __restrict__ lens,
    float* __restrict__ part, float* __restrict__ wsum)
{
  __shared__ __align__(16) short As[2][BM*BK];   // 4KB x2
  __shared__ __align__(16) short Bs[2][BN*BK];   // 32KB x2
  __shared__ float wqs[DQ];                       // 4KB
  __shared__ float red[8][BM];                    // 2KB
  __shared__ float wrow[BM];
  __shared__ float xqrow[BM];

  int tid = threadIdx.x;
  int bm = blockIdx.x;
  int m0 = bm*BM;
  int batch = bm >> 5;          // 32 s-chunks of 64 per batch
  int s0 = (bm & 31) * 64;
  int lane = tid & 63, wid = tid >> 6;
  int wn = wid;                 // 8 waves across N=512
  int lo = lane & 15, hi = lane >> 4;

  wqs[tid]     = wq[tid];
  wqs[tid+512] = wq[tid+512];

  // A staging: thread t -> row t>>3 (0..63), cols (t&7)*4 .. +4
  int ar = tid >> 3, ac = (tid & 7) * 4;
  const float* asrc = x + (size_t)(m0 + ar)*DQ + ac;
  // B staging: issue i covers rows i*128+(t>>2); LDS shorts i*4096 + t*8
  const short* bsrc = w1t + (size_t)(tid>>2)*DQ + (tid&3)*8;

  float w2v[4], b1v[4];
  #pragma unroll
  for (int fn=0;fn<4;fn++){
    int n = wn*64 + fn*16 + lo;
    w2v[fn] = w2[n]; b1v[fn] = b1[n];
  }

  // ---- prologue: stage k0=0
  f32x4 r0 = *(const f32x4*)(asrc);
  #pragma unroll
  for (int i=0;i<4;i++)
    gload_lds16(bsrc + (size_t)i*128*DQ, &Bs[0][i*4096 + tid*8]);
  __syncthreads();   // wqs visible; Bs[0] drained (barrier implies vmcnt(0))
  float xqacc = 0.f;
  {
    f32x4 w0 = *(const f32x4*)(wqs + ac);
    #pragma unroll
    for (int j=0;j<4;j++) xqacc += r0[j]*w0[j];
    bf16x4 s0v;
    #pragma unroll
    for (int j=0;j<4;j++) s0v[j]=f2bf(r0[j]);
    *(bf16x4*)(&As[0][ar*BK + ac]) = s0v;
  }
  __syncthreads();

  f32x4 acc[4][4];
  #pragma unroll
  for (int a=0;a<4;a++)
    #pragma unroll
    for (int b=0;b<4;b++) acc[a][b] = (f32x4){0.f,0.f,0.f,0.f};

  for (int t=0;t<32;t++){
    int cur = t & 1, nxt = cur ^ 1;
    int k0n = (t+1)*BK;
    if (t < 31){
      r0 = *(const f32x4*)(asrc + k0n);
      #pragma unroll
      for (int i=0;i<4;i++)
        gload_lds16(bsrc + (size_t)i*128*DQ + k0n, &Bs[nxt][i*4096 + tid*8]);
    }
    bf16x8 af[4], bfr[4];
    #pragma unroll
    for (int fm=0;fm<4;fm++)
      af[fm] = *(const bf16x8*)(&As[cur][(fm*16+lo)*BK + hi*8]);
    #pragma unroll
    for (int fn=0;fn<4;fn++)
      bfr[fn] = *(const bf16x8*)(&Bs[cur][(wn*64+fn*16+lo)*BK + hi*8]);
    #pragma unroll
    for (int fm=0;fm<4;fm++)
      #pragma unroll
      for (int fn=0;fn<4;fn++)
        acc[fm][fn] = __builtin_amdgcn_mfma_f32_16x16x32_bf16(af[fm], bfr[fn], acc[fm][fn], 0,0,0);
    if (t < 31){
      f32x4 w0 = *(const f32x4*)(wqs + k0n + ac);
      #pragma unroll
      for (int j=0;j<4;j++) xqacc += r0[j]*w0[j];
      bf16x4 s0v;
      #pragma unroll
      for (int j=0;j<4;j++) s0v[j]=f2bf(r0[j]);
      *(bf16x4*)(&As[nxt][ar*BK + ac]) = s0v;
    }
    __syncthreads();
  }

  // xq: combine 8 threads per row
  {
    float s = xqacc;
    s += __shfl_xor(s,1); s += __shfl_xor(s,2); s += __shfl_xor(s,4);
    if ((tid & 7) == 0) xqrow[ar] = s;
  }

  // gate partials: GELU + dot w2 over this wave's 64 cols
  #pragma unroll
  for (int fm=0;fm<4;fm++){
    #pragma unroll
    for (int j=0;j<4;j++){
      float s = 0.f;
      #pragma unroll
      for (int fn=0;fn<4;fn++){
        float h = acc[fm][fn][j] + b1v[fn];
        float g = 0.5f*h*(1.0f + erff(h*0.70710678118f));
        s += g*w2v[fn];
      }
      s += __shfl_xor(s,1); s += __shfl_xor(s,2);
      s += __shfl_xor(s,4); s += __shfl_xor(s,8);
      if (lo == 0) red[wid][fm*16 + hi*4 + j] = s;
    }
  }
  __syncthreads();

  // w phase: wave 0 computes e=exp(dec) (denominator) and wrow=e*gate (numerator)
  if (tid < 64){
    int s = s0 + tid;
    float gsum = b2p[0];
    #pragma unroll
    for (int w=0;w<8;w++) gsum += red[w][tid];
    float gate = 1.0f/(1.0f+expf(-gsum));
    float qb = wq[DQ];
    float lg = (gate*xqrow[tid] + qb)*0.03125f;
    float lam = lamp[0];
    float posl = fmaxf(lam,0.f) + log1pf(expf(-fabsf(lam)));
    int L = lens[batch];
    float pen = fmaxf((float)L - 1.0f - (float)s, 0.0f);
    int fl = *flag;
    size_t mi_ = (size_t)batch*SQ + s;
    int mm = (fl==2) ? (((const unsigned char*)maskp)[mi_]!=0)
           : (fl==1) ? (((const float*)maskp)[mi_]!=0.0f)
                     : (((const int*)maskp)[mi_]!=0);
    float e = mm ? 0.0f : expf(lg - posl*pen);   // softmax numerator term
    wrow[tid] = e*gate;                           // pooling weight
    float tsum = e;                               // softmax denominator term
    #pragma unroll
    for (int o=1;o<64;o<<=1) tsum += __shfl_xor(tsum,o);
    if (tid==0) wsum[bm] = tsum;
  }
  __syncthreads();

  // pooling: part[bm][d] = sum_s wrow_s * x[m0+s][d]  (x tile is L2-hot)
  {
    int d0 = tid*2;
    const float* xb = x + (size_t)m0*DQ + d0;
    float a0=0.f, a1=0.f;
    #pragma unroll 8
    for (int s=0;s<64;s++){
      float w = wrow[s];
      float2 v = *(const float2*)(xb + (size_t)s*DQ);
      a0 += w*v.x; a1 += w*v.y;
    }
    *(float2*)(part + (size_t)bm*DQ + d0) = make_float2(a0,a1);
  }
}

// ---- final: out[b][d] = sum_c part[b*32+c][d] / sum_c wsum[b*32+c]
__global__ __launch_bounds__(256) void k_fin(const float* __restrict__ part,
                                             const float* __restrict__ wsum,
                                             float* __restrict__ out){
  int i = blockIdx.x*256 + threadIdx.x;   // 32768
  int b = i >> 10, d = i & 1023;
  float den = 0.f;
  #pragma unroll
  for (int c=0;c<32;c++) den += wsum[b*32+c];
  float s = 0.f;
  #pragma unroll
  for (int c=0;c<32;c++) s += part[((size_t)(b*32+c))*DQ + d];
  out[i] = s/den;
}

extern "C" void kernel_launch(void* const* d_in, const int* in_sizes, int n_in,
                              void* d_out, int out_size, void* d_ws, size_t ws_size,
                              hipStream_t stream)
{
  const float* x    = (const float*)d_in[0];
  const void*  mask = d_in[1];
  const float* w1   = (const float*)d_in[2];
  const float* b1   = (const float*)d_in[3];
  const float* w2   = (const float*)d_in[4];
  const float* b2   = (const float*)d_in[5];
  const float* lam  = (const float*)d_in[6];
  const float* q    = (const float*)d_in[7];
  const float* kw   = (const float*)d_in[8];
  const float* kb   = (const float*)d_in[9];
  char* ws = (char*)d_ws;
  short* w1t = (short*)ws;                               // 1 MB
  float* wq  = (float*)(ws + (1<<20));                   // 8 KB (1025 floats)
  int* flag  = (int*)(ws + (1<<20) + 8192);              // 4 B
  int* lens  = (int*)(ws + (1<<20) + 8448);              // 128 B
  float* wsum= (float*)(ws + (1<<20) + 12544);           // 4 KB (1024 floats)
  float* part= (float*)(ws + (1<<20) + 20736);           // 4 MB
  float* out = (float*)d_out;

  k_w1t<<<dim3((NQ*DQ+255)/256), 256, 0, stream>>>(w1, w1t);
  k_wq<<<dim3(DQ+1), 256, 0, stream>>>(kw, kb, q, wq);
  k_det<<<dim3(1), 256, 0, stream>>>((const unsigned int*)mask, flag);
  k_len<<<dim3(BQ), 256, 0, stream>>>(mask, flag, lens);
  k_gate<<<dim3(MQ/BM), 512, 0, stream>>>(x, w1t, wq, w2, b1, b2, lam,
                                          mask, flag, lens, part, wsum);
  k_fin<<<dim3((BQ*DQ)/256), 256, 0, stream>>>(part, wsum, out);
}

// Round 8
// 184.807 us; speedup vs baseline: 2.4614x; 1.0028x over previous
//
#include <hip/hip_runtime.h>
#include <hip/hip_bf16.h>
#include <math.h>

#define BQ 32
#define SQ 2048
#define DQ 1024
#define NQ 512
#define MQ (BQ*SQ)
#define BM 64
#define BN 512
#define BK 32

typedef __attribute__((ext_vector_type(8))) short bf16x8;
typedef __attribute__((ext_vector_type(4))) short bf16x4;
typedef __attribute__((ext_vector_type(4))) float f32x4;

#define WAITVM(n) asm volatile("s_waitcnt vmcnt(" #n ")")
#define WAITLG    asm volatile("s_waitcnt lgkmcnt(0)")
#define SB0       __builtin_amdgcn_sched_barrier(0)

// compiler-path f32->bf16 (RTNE, pairs into v_cvt_pk_bf16_f32)
__device__ __forceinline__ short f2bf(float f){
  return __builtin_bit_cast(short, __float2bfloat16(f));
}

__device__ __forceinline__ void gload_lds16(const void* g, void* l){
  __builtin_amdgcn_global_load_lds(
      (const __attribute__((address_space(1))) unsigned int*)g,
      (__attribute__((address_space(3))) unsigned int*)l, 16, 0, 0);
}

// ---- prep: transpose gate_w1 [K=1024][N=512] -> bf16 w1t [N=512][K=1024]
__global__ void k_w1t(const float* __restrict__ w1, short* __restrict__ w1t){
  int i = blockIdx.x*256 + threadIdx.x;
  if (i >= NQ*DQ) return;
  int n = i >> 10, k = i & (DQ-1);
  w1t[i] = f2bf(w1[(size_t)k*NQ + n]);
}

// ---- prep: wq[d] = key_w[d,:]·q (d<1024); wq[1024] = key_b·q
__global__ void k_wq(const float* __restrict__ kw, const float* __restrict__ kb,
                     const float* __restrict__ q, float* __restrict__ wq){
  __shared__ float sh[4];
  int d = blockIdx.x, t = threadIdx.x;
  const float* row = (d < DQ) ? (kw + (size_t)d*DQ) : kb;
  float s = 0.f;
  for (int e=t;e<DQ;e+=256) s += row[e]*q[e];
  #pragma unroll
  for (int o=32;o;o>>=1) s += __shfl_down(s,o);
  if ((t&63)==0) sh[t>>6]=s;
  __syncthreads();
  if (t==0) wq[d] = sh[0]+sh[1]+sh[2]+sh[3];
}

// ---- mask dtype detector: 0=int32(0/1), 1=float32(0/1.0f), 2=byte(bool)
__global__ void k_det(const unsigned int* __restrict__ m, int* __restrict__ flag){
  __shared__ int so, sf;
  int t = threadIdx.x;
  if (t==0){ so=0; sf=0; }
  __syncthreads();
  int o=0, f1=0;
  for (int i=t;i<MQ/4;i+=256){
    unsigned v = m[i];
    if (v==0x3F800000u) f1=1;
    else if (v>1u) o=1;
  }
  if (o) atomicOr(&so,1);
  if (f1) atomicOr(&sf,1);
  __syncthreads();
  if (t==0) *flag = so?2:(sf?1:0);
}

// ---- per-batch valid length (reads flag; stream-ordered after k_det)
__global__ __launch_bounds__(256) void k_len(const void* __restrict__ maskp,
                                             const int* __restrict__ flag,
                                             int* __restrict__ lens){
  __shared__ int sh[4];
  int b = blockIdx.x, t = threadIdx.x;
  int fl = *flag;
  const unsigned char* m8 = (const unsigned char*)maskp;
  const float* mf = (const float*)maskp;
  const int* mi = (const int*)maskp;
  int cnt = 0;
  #pragma unroll
  for (int i=0;i<8;i++){
    size_t idx = (size_t)b*SQ + t + i*256;
    int mm = (fl==2) ? (m8[idx]!=0) : (fl==1) ? (mf[idx]!=0.0f) : (mi[idx]!=0);
    cnt += mm^1;
  }
  #pragma unroll
  for (int o=32;o;o>>=1) cnt += __shfl_down(cnt,o);
  if ((t&63)==0) sh[t>>6]=cnt;
  __syncthreads();
  if (t==0) lens[b] = sh[0]+sh[1]+sh[2]+sh[3];
}

// ---- fused: h=x@W1 (MFMA, 4-phase counted-vmcnt pipeline) -> gate ->
//      e=exp(dec), w=e*gate -> partial pool.
// 64x512 tile (full N), BK=32, 512 threads = 8 waves over N, wave tile 64x64.
// Bs quartered by fn (phase q holds cols wn*64+q*16+lo for all wn); phase q of
// step t stages quarter q of tile t+1 and MFMAs frag fn=q of tile t.
__global__ __launch_bounds__(512, 4) void k_gate(
    const float* __restrict__ x, const short* __restrict__ w1t,
    const float* __restrict__ wq, const float* __restrict__ w2,
    const float* __restrict__ b1, const float* __restrict__ b2p,
    const float* __restrict__ lamp,
    const void* __restrict__ maskp, const int* __restrict__ flag,
    const int* __restrict__ lens,
    float* __restrict__ part, float* __restrict__ wsum)
{
  __shared__ __align__(16) short As[2][BM*BK];     // 4KB x2
  __shared__ __align__(16) short Bs[2][BN*BK];     // 32KB x2, quartered
  __shared__ float wqs[DQ];                         // 4KB
  __shared__ float red[8][BM];                      // 2KB
  __shared__ float wrow[BM];
  __shared__ float xqrow[BM];

  int tid = threadIdx.x;
  int bm = blockIdx.x;
  int m0 = bm*BM;
  int batch = bm >> 5;          // 32 s-chunks of 64 per batch
  int sBase = (bm & 31) * 64;
  int lane = tid & 63, wid = tid >> 6;
  int wn = wid;                 // 8 waves across N=512
  int lo = lane & 15, hi = lane >> 4;

  wqs[tid]     = wq[tid];
  wqs[tid+512] = wq[tid+512];

  // A staging: thread t -> row t>>3 (0..63), cols (t&3... (t&7)*4 .. +4
  int ar = tid >> 3, ac = (tid & 7) * 4;
  const float* asrc = x + (size_t)(m0 + ar)*DQ + ac;
  // B staging (quartered): thread t covers quarter-row r=t>>2,
  // global col n = (r>>4)*64 + q*16 + (r&15), k-chunk (t&3)*8.
  int br = tid >> 2;
  int base_n = ((br >> 4) << 6) | (br & 15);
  const short* bsrc0 = w1t + (size_t)base_n*DQ + (tid&3)*8;

  // LDS read offsets (shorts)
  int boff  = (wn*16 + lo)*BK + hi*8;   // within a quarter
  int aoff0 = (0*16 + lo)*BK + hi*8;
  int aoff1 = (1*16 + lo)*BK + hi*8;
  int aoff2 = (2*16 + lo)*BK + hi*8;
  int aoff3 = (3*16 + lo)*BK + hi*8;

  float w2v[4], b1v[4];
  #pragma unroll
  for (int fn=0;fn<4;fn++){
    int n = wn*64 + fn*16 + lo;
    w2v[fn] = w2[n]; b1v[fn] = b1[n];
  }

  __syncthreads();   // wqs visible to all (full drain, one-time)

  // ---- prologue: issue A0, B0q0-2, A1, B0q3; convert A0 into As[0]
  float xqacc = 0.f;
  f32x4 rA1, rA2 = (f32x4){0.f,0.f,0.f,0.f};
  {
    f32x4 rA0 = *(const f32x4*)(asrc);
    gload_lds16(bsrc0,          &Bs[0][0*4096 + tid*8]);
    gload_lds16(bsrc0 + 16*DQ,  &Bs[0][1*4096 + tid*8]);
    gload_lds16(bsrc0 + 32*DQ,  &Bs[0][2*4096 + tid*8]);
    rA1 = *(const f32x4*)(asrc + BK);
    gload_lds16(bsrc0 + 48*DQ,  &Bs[0][3*4096 + tid*8]);
    f32x4 w0 = *(const f32x4*)(wqs + ac);
    xqacc += rA0[0]*w0[0] + rA0[1]*w0[1] + rA0[2]*w0[2] + rA0[3]*w0[3];
    bf16x4 sv;
    sv[0]=f2bf(rA0[0]); sv[1]=f2bf(rA0[1]); sv[2]=f2bf(rA0[2]); sv[3]=f2bf(rA0[3]);
    *(bf16x4*)(&As[0][ar*BK + ac]) = sv;
    WAITLG; SB0;
  }

  f32x4 acc[4][4];
  #pragma unroll
  for (int a=0;a<4;a++)
    #pragma unroll
    for (int b=0;b<4;b++) acc[a][b] = (f32x4){0.f,0.f,0.f,0.f};

  bf16x8 af[4];

#define PHASE_CORE(qq) do{                                                      \
    __builtin_amdgcn_s_barrier(); SB0;                                          \
    bf16x8 _b = *(const bf16x8*)(&Bs[cur][(qq)*4096 + boff]);                   \
    if ((qq)==0){                                                               \
      af[0] = *(const bf16x8*)(&As[cur][aoff0]);                                \
      af[1] = *(const bf16x8*)(&As[cur][aoff1]);                                \
      af[2] = *(const bf16x8*)(&As[cur][aoff2]);                                \
      af[3] = *(const bf16x8*)(&As[cur][aoff3]);                                \
    }                                                                           \
    WAITLG; SB0;                                                                \
    __builtin_amdgcn_s_setprio(1);                                              \
    acc[0][qq] = __builtin_amdgcn_mfma_f32_16x16x32_bf16(af[0], _b, acc[0][qq],0,0,0); \
    acc[1][qq] = __builtin_amdgcn_mfma_f32_16x16x32_bf16(af[1], _b, acc[1][qq],0,0,0); \
    acc[2][qq] = __builtin_amdgcn_mfma_f32_16x16x32_bf16(af[2], _b, acc[2][qq],0,0,0); \
    acc[3][qq] = __builtin_amdgcn_mfma_f32_16x16x32_bf16(af[3], _b, acc[3][qq],0,0,0); \
    __builtin_amdgcn_s_setprio(0);                                              \
  }while(0)

  for (int t=0; t<31; ++t){
    int cur = t&1, nxt = cur^1;
    int kn = (t+1)*BK;
    const short* bK = bsrc0 + kn;
    short* BsN = &Bs[nxt][0];
    // phase 0
    gload_lds16(bK,           BsN + 0*4096 + tid*8);
    SB0; WAITVM(5); SB0;
    PHASE_CORE(0);
    // phase 1
    gload_lds16(bK + 16*DQ,   BsN + 1*4096 + tid*8);
    SB0; WAITVM(5); SB0;
    PHASE_CORE(1);
    // phase 2 (+ A prefetch, distance 2)
    gload_lds16(bK + 32*DQ,   BsN + 2*4096 + tid*8);
    if (t < 30){
      rA2 = *(const f32x4*)(asrc + (t+2)*BK);
      SB0; WAITVM(6); SB0;
    } else {
      SB0; WAITVM(5); SB0;
    }
    PHASE_CORE(2);
    // phase 3
    gload_lds16(bK + 48*DQ,   BsN + 3*4096 + tid*8);
    if (t < 30){ SB0; WAITVM(5); SB0; } else { SB0; WAITVM(4); SB0; }
    PHASE_CORE(3);
    // A epilogue: tile t+1 -> As[nxt]; fused xq dot
    {
      f32x4 w0 = *(const f32x4*)(wqs + kn + ac);
      xqacc += rA1[0]*w0[0] + rA1[1]*w0[1] + rA1[2]*w0[2] + rA1[3]*w0[3];
      bf16x4 sv;
      sv[0]=f2bf(rA1[0]); sv[1]=f2bf(rA1[1]); sv[2]=f2bf(rA1[2]); sv[3]=f2bf(rA1[3]);
      *(bf16x4*)(&As[nxt][ar*BK + ac]) = sv;
      WAITLG; SB0;
      rA1 = rA2;
    }
  }
  { // t = 31 (drain tail)
    int cur = 1;
    SB0; WAITVM(3); SB0; PHASE_CORE(0);
    SB0; WAITVM(2); SB0; PHASE_CORE(1);
    SB0; WAITVM(1); SB0; PHASE_CORE(2);
    SB0; WAITVM(0); SB0; PHASE_CORE(3);
  }
#undef PHASE_CORE

  // xq: combine 8 threads per row
  {
    float s = xqacc;
    s += __shfl_xor(s,1); s += __shfl_xor(s,2); s += __shfl_xor(s,4);
    if ((tid & 7) == 0) xqrow[ar] = s;
  }

  // gate partials: GELU + dot w2 over this wave's 64 cols
  #pragma unroll
  for (int fm=0;fm<4;fm++){
    #pragma unroll
    for (int j=0;j<4;j++){
      float s = 0.f;
      #pragma unroll
      for (int fn=0;fn<4;fn++){
        float h = acc[fm][fn][j] + b1v[fn];
        float g = 0.5f*h*(1.0f + erff(h*0.70710678118f));
        s += g*w2v[fn];
      }
      s += __shfl_xor(s,1); s += __shfl_xor(s,2);
      s += __shfl_xor(s,4); s += __shfl_xor(s,8);
      if (lo == 0) red[wid][fm*16 + hi*4 + j] = s;
    }
  }
  __syncthreads();

  // w phase: wave 0 computes e=exp(dec) (denominator) and wrow=e*gate (numerator)
  if (tid < 64){
    int s = sBase + tid;
    float gsum = b2p[0];
    #pragma unroll
    for (int w=0;w<8;w++) gsum += red[w][tid];
    float gate = 1.0f/(1.0f+expf(-gsum));
    float qb = wq[DQ];
    float lg = (gate*xqrow[tid] + qb)*0.03125f;
    float lam = lamp[0];
    float posl = fmaxf(lam,0.f) + log1pf(expf(-fabsf(lam)));
    int L = lens[batch];
    float pen = fmaxf((float)L - 1.0f - (float)s, 0.0f);
    int fl = *flag;
    size_t mi_ = (size_t)batch*SQ + s;
    int mm = (fl==2) ? (((const unsigned char*)maskp)[mi_]!=0)
           : (fl==1) ? (((const float*)maskp)[mi_]!=0.0f)
                     : (((const int*)maskp)[mi_]!=0);
    float e = mm ? 0.0f : expf(lg - posl*pen);   // softmax numerator term
    wrow[tid] = e*gate;                           // pooling weight
    float tsum = e;                               // softmax denominator term
    #pragma unroll
    for (int o=1;o<64;o<<=1) tsum += __shfl_xor(tsum,o);
    if (tid==0) wsum[bm] = tsum;
  }
  __syncthreads();

  // pooling: part[bm][d] = sum_s wrow_s * x[m0+s][d]  (x tile is L2/L3-hot)
  {
    int d0 = tid*2;
    const float* xb = x + (size_t)m0*DQ + d0;
    float a0=0.f, a1=0.f;
    #pragma unroll 8
    for (int s=0;s<64;s++){
      float w = wrow[s];
      float2 v = *(const float2*)(xb + (size_t)s*DQ);
      a0 += w*v.x; a1 += w*v.y;
    }
    *(float2*)(part + (size_t)bm*DQ + d0) = make_float2(a0,a1);
  }
}

// ---- final: out[b][d] = sum_c part[b*32+c][d] / sum_c wsum[b*32+c]
__global__ __launch_bounds__(256) void k_fin(const float* __restrict__ part,
                                             const float* __restrict__ wsum,
                                             float* __restrict__ out){
  int i = blockIdx.x*256 + threadIdx.x;   // 32768
  int b = i >> 10, d = i & 1023;
  float den = 0.f;
  #pragma unroll
  for (int c=0;c<32;c++) den += wsum[b*32+c];
  float s = 0.f;
  #pragma unroll
  for (int c=0;c<32;c++) s += part[((size_t)(b*32+c))*DQ + d];
  out[i] = s/den;
}

extern "C" void kernel_launch(void* const* d_in, const int* in_sizes, int n_in,
                              void* d_out, int out_size, void* d_ws, size_t ws_size,
                              hipStream_t stream)
{
  const float* x    = (const float*)d_in[0];
  const void*  mask = d_in[1];
  const float* w1   = (const float*)d_in[2];
  const float* b1   = (const float*)d_in[3];
  const float* w2   = (const float*)d_in[4];
  const float* b2   = (const float*)d_in[5];
  const float* lam  = (const float*)d_in[6];
  const float* q    = (const float*)d_in[7];
  const float* kw   = (const float*)d_in[8];
  const float* kb   = (const float*)d_in[9];
  char* ws = (char*)d_ws;
  short* w1t = (short*)ws;                               // 1 MB
  float* wq  = (float*)(ws + (1<<20));                   // 8 KB (1025 floats)
  int* flag  = (int*)(ws + (1<<20) + 8192);              // 4 B
  int* lens  = (int*)(ws + (1<<20) + 8448);              // 128 B
  float* wsum= (float*)(ws + (1<<20) + 12544);           // 4 KB (1024 floats)
  float* part= (float*)(ws + (1<<20) + 20736);           // 4 MB
  float* out = (float*)d_out;

  k_w1t<<<dim3((NQ*DQ+255)/256), 256, 0, stream>>>(w1, w1t);
  k_wq<<<dim3(DQ+1), 256, 0, stream>>>(kw, kb, q, wq);
  k_det<<<dim3(1), 256, 0, stream>>>((const unsigned int*)mask, flag);
  k_len<<<dim3(BQ), 256, 0, stream>>>(mask, flag, lens);
  k_gate<<<dim3(MQ/BM), 512, 0, stream>>>(x, w1t, wq, w2, b1, b2, lam,
                                          mask, flag, lens, part, wsum);
  k_fin<<<dim3((BQ*DQ)/256), 256, 0, stream>>>(part, wsum, out);
}